// Round 1
// 233.313 us; speedup vs baseline: 1.0136x; 1.0136x over previous
//
#include <hip/hip_runtime.h>

#define N_USER 50000
#define N_ITEM 50000
#define N_NODE 50000
#define N_EDGE 1600000
#define D 64

#define FB_SHIFT 7        // 128 nodes per fine bucket
#define N_FINE 400        // covers 51200 >= 50000 nodes
#define CAP 5120          // per-bucket edge capacity (mean 4096 -> 16 sigma headroom)
#define BIN_CHUNK 2048    // edges per bin block (4x parallelism vs 8192)
#define NCAST 3125        // cast blocks per table: 50000*16/256 exactly
#define NBIN ((N_EDGE + BIN_CHUNK - 1) / BIN_CHUNK)   // 782

typedef __attribute__((ext_vector_type(8))) short short8;    // 8 bf16 = 4 VGPR
typedef __attribute__((ext_vector_type(4))) float floatx4;   // mfma acc

__device__ __forceinline__ unsigned short f32_to_bf16(float x) {
    unsigned u = __float_as_uint(x);
    unsigned r = (u + 0x7FFFu + ((u >> 16) & 1u)) >> 16;   // RNE
    return (unsigned short)r;
}
__device__ __forceinline__ float bf16_to_f32(unsigned short h) {
    return __uint_as_float(((unsigned)h) << 16);
}

// ---------------------------------------------------------------------------
// Kernel 1 (merged): 1-D grid. Blocks [0, 2*NBIN) run fine binning (multisplit
// into fixed-capacity bucket windows) — dispatched FIRST so the latency-bound
// phase starts at t=0 with maximum resident waves. Blocks [2*NBIN, ...) cast
// fp32->bf16 feature tables (BW-bound, overlaps under the binning latency).
// fcur holds per-bucket COUNTS (memset 0); window base is f*CAP added at
// reservation.
// ---------------------------------------------------------------------------
__global__ __launch_bounds__(256) void cast_bin(
    const float4* __restrict__ fU, ushort4* __restrict__ bU,
    const float4* __restrict__ fI, ushort4* __restrict__ bI,
    const int* __restrict__ srcA, const int* __restrict__ dstA, unsigned* __restrict__ binA,
    const int* __restrict__ srcB, const int* __restrict__ dstB, unsigned* __restrict__ binB,
    int* __restrict__ fcur)
{
    __shared__ int hist[N_FINE];
    __shared__ int lcur[N_FINE];
    const int id = blockIdx.x;

    if (id >= 2 * NBIN) {
        // cast role: pure streaming, exact bounds (NCAST*256 == N_NODE*16)
        const int cid = id - 2 * NBIN;
        const int et = (cid >= NCAST) ? 1 : 0;
        const float4* __restrict__ in = et ? fI : fU;
        ushort4* __restrict__ out     = et ? bI : bU;
        int i = (cid - et * NCAST) * 256 + threadIdx.x;
        float4 v = in[i];
        ushort4 o;
        o.x = f32_to_bf16(v.x); o.y = f32_to_bf16(v.y);
        o.z = f32_to_bf16(v.z); o.w = f32_to_bf16(v.w);
        out[i] = o;
        return;
    }

    // fine_bin role — blocks [0, 2*NBIN), all resident from t=0
    const int et = (id >= NBIN) ? 1 : 0;
    const int chunk = id - et * NBIN;
    const int* __restrict__ src = et ? srcB : srcA;
    const int* __restrict__ dst = et ? dstB : dstA;
    unsigned* __restrict__ bin  = et ? binB : binA;
    int* __restrict__ fc = fcur + et * N_FINE;

    for (int i = threadIdx.x; i < N_FINE; i += 256) hist[i] = 0;
    __syncthreads();

    const int base = chunk * BIN_CHUNK;
    const int n4 = (min(BIN_CHUNK, N_EDGE - base)) >> 2;   // N_EDGE % 4 == 0
    const int4* dst4 = (const int4*)(dst + base);
    const int4* src4 = (const int4*)(src + base);

    // pass 1: count
    for (int i = threadIdx.x; i < n4; i += 256) {
        int4 d = dst4[i];
        atomicAdd(&hist[d.x >> FB_SHIFT], 1);
        atomicAdd(&hist[d.y >> FB_SHIFT], 1);
        atomicAdd(&hist[d.z >> FB_SHIFT], 1);
        atomicAdd(&hist[d.w >> FB_SHIFT], 1);
    }
    __syncthreads();
    // reserve contiguous windows (base f*CAP + running count)
    for (int f = threadIdx.x; f < N_FINE; f += 256) {
        int c = hist[f];
        lcur[f] = c ? (f * CAP + atomicAdd(&fc[f], c)) : 0;
    }
    __syncthreads();
    // pass 2: scatter packed (dst<<16)|src
    for (int i = threadIdx.x; i < n4; i += 256) {
        int4 d = dst4[i];
        int4 s = src4[i];
        { int pos = atomicAdd(&lcur[d.x >> FB_SHIFT], 1); bin[pos] = ((unsigned)d.x << 16) | (unsigned)s.x; }
        { int pos = atomicAdd(&lcur[d.y >> FB_SHIFT], 1); bin[pos] = ((unsigned)d.y << 16) | (unsigned)s.y; }
        { int pos = atomicAdd(&lcur[d.z >> FB_SHIFT], 1); bin[pos] = ((unsigned)d.z << 16) | (unsigned)s.z; }
        { int pos = atomicAdd(&lcur[d.w >> FB_SHIFT], 1); bin[pos] = ((unsigned)d.w << 16) | (unsigned)s.w; }
    }
}

// ---------------------------------------------------------------------------
// Kernel 2: per-bucket counting sort -> u16 srt + off/cnt. 1.5 KB LDS.
// ---------------------------------------------------------------------------
__global__ __launch_bounds__(256) void bucket_sort(
    const unsigned* __restrict__ binI, unsigned short* __restrict__ srtI,
    int* __restrict__ offI, int* __restrict__ cntI,
    const unsigned* __restrict__ binU, unsigned short* __restrict__ srtU,
    int* __restrict__ offU, int* __restrict__ cntU,
    const int* __restrict__ fcur)
{
    const int et = blockIdx.y;
    const unsigned* __restrict__ bin = et ? binU : binI;
    unsigned short* __restrict__ srt = et ? srtU : srtI;
    int* __restrict__ off  = et ? offU : offI;
    int* __restrict__ cntG = et ? cntU : cntI;
    const int f = blockIdx.x;
    const int start = f * CAP;
    const int end   = start + fcur[et * N_FINE + f];   // fcur holds counts
    const int nodebase = f << FB_SHIFT;

    __shared__ int cnt[128];
    __shared__ int sc[128];
    __shared__ int pos[128];
    if (threadIdx.x < 128) cnt[threadIdx.x] = 0;
    __syncthreads();

    for (int e = start + threadIdx.x; e < end; e += 256) {
        int ld = (int)(bin[e] >> 16) - nodebase;
        atomicAdd(&cnt[ld], 1);
    }
    __syncthreads();

    if (threadIdx.x < 128) sc[threadIdx.x] = cnt[threadIdx.x];
    __syncthreads();
    for (int o = 1; o < 128; o <<= 1) {
        int t = 0;
        if (threadIdx.x < 128 && threadIdx.x >= o) t = sc[threadIdx.x - o];
        __syncthreads();
        if (threadIdx.x < 128) sc[threadIdx.x] += t;
        __syncthreads();
    }
    if (threadIdx.x < 128) {
        int base = start + sc[threadIdx.x] - cnt[threadIdx.x];   // absolute excl
        pos[threadIdx.x] = base;
        int node = nodebase + threadIdx.x;
        if (node < N_NODE) { off[node] = base; cntG[node] = cnt[threadIdx.x]; }
    }
    __syncthreads();

    for (int e = start + threadIdx.x; e < end; e += 256) {
        unsigned p = bin[e];
        int ld = (int)(p >> 16) - nodebase;
        int q = atomicAdd(&pos[ld], 1);
        srt[q] = (unsigned short)(p & 0xFFFFu);
    }
}

// ---------------------------------------------------------------------------
// Kernel 3: raw-feature segment mean (bf16 gather). No LDS, 16 lanes/node,
// ushort4 per lane (128 B per edge), unroll-4 for memory-level parallelism.
// ---------------------------------------------------------------------------
__global__ __launch_bounds__(256) void aggregate_kernel(
    const ushort4* __restrict__ itemB,   // sources for user dst (rev)
    const ushort4* __restrict__ userB,   // sources for item dst (rate)
    const int* __restrict__ offU, const int* __restrict__ cntU, const unsigned short* __restrict__ srtU,
    const int* __restrict__ offI, const int* __restrict__ cntI, const unsigned short* __restrict__ srtI,
    ushort4* __restrict__ aggU, ushort4* __restrict__ aggI)
{
    int g = blockIdx.x * 16 + (threadIdx.x >> 4);
    if (g >= N_USER + N_ITEM) return;
    const int lane = threadIdx.x & 15;

    const bool isUser = (g < N_USER);
    const int d = isUser ? g : g - N_USER;
    const ushort4* __restrict__ tab = isUser ? itemB : userB;
    const int* __restrict__ off     = isUser ? offU : offI;
    const int* __restrict__ cntG    = isUser ? cntU : cntI;
    const unsigned short* __restrict__ srt = isUser ? srtU : srtI;
    ushort4* __restrict__ agg       = isUser ? aggU : aggI;

    const int start = off[d];
    const int c     = cntG[d];
    const int end   = start + c;

    float4 a0 = make_float4(0.f, 0.f, 0.f, 0.f);
    float4 a1 = make_float4(0.f, 0.f, 0.f, 0.f);
    float4 a2 = make_float4(0.f, 0.f, 0.f, 0.f);
    float4 a3 = make_float4(0.f, 0.f, 0.f, 0.f);
    int e = start;
    for (; e + 4 <= end; e += 4) {
        int s0 = (int)srt[e],     s1 = (int)srt[e + 1];
        int s2 = (int)srt[e + 2], s3 = (int)srt[e + 3];
        ushort4 w0 = tab[(size_t)s0 * 16 + lane];
        ushort4 w1 = tab[(size_t)s1 * 16 + lane];
        ushort4 w2 = tab[(size_t)s2 * 16 + lane];
        ushort4 w3 = tab[(size_t)s3 * 16 + lane];
        a0.x += bf16_to_f32(w0.x); a0.y += bf16_to_f32(w0.y);
        a0.z += bf16_to_f32(w0.z); a0.w += bf16_to_f32(w0.w);
        a1.x += bf16_to_f32(w1.x); a1.y += bf16_to_f32(w1.y);
        a1.z += bf16_to_f32(w1.z); a1.w += bf16_to_f32(w1.w);
        a2.x += bf16_to_f32(w2.x); a2.y += bf16_to_f32(w2.y);
        a2.z += bf16_to_f32(w2.z); a2.w += bf16_to_f32(w2.w);
        a3.x += bf16_to_f32(w3.x); a3.y += bf16_to_f32(w3.y);
        a3.z += bf16_to_f32(w3.z); a3.w += bf16_to_f32(w3.w);
    }
    for (; e < end; ++e) {
        int s0 = (int)srt[e];
        ushort4 w0 = tab[(size_t)s0 * 16 + lane];
        a0.x += bf16_to_f32(w0.x); a0.y += bf16_to_f32(w0.y);
        a0.z += bf16_to_f32(w0.z); a0.w += bf16_to_f32(w0.w);
    }
    a0.x += a1.x + a2.x + a3.x;
    a0.y += a1.y + a2.y + a3.y;
    a0.z += a1.z + a2.z + a3.z;
    a0.w += a1.w + a2.w + a3.w;

    const float inv = (c > 0) ? 1.0f / (float)c : 0.0f;
    ushort4 o;
    o.x = f32_to_bf16(a0.x * inv);
    o.y = f32_to_bf16(a0.y * inv);
    o.z = f32_to_bf16(a0.z * inv);
    o.w = f32_to_bf16(a0.w * inv);
    agg[(size_t)g * 16 + lane - (isUser ? 0 : (size_t)N_USER * 16)] = o;
}

// ---------------------------------------------------------------------------
// Kernel 4: final dual GEMM via MFMA (16x16x32 bf16). 64 rows/block, 4 waves.
// D = agg@W + feat@loop (+ biases in epilogue). Layouts guide-verified.
// ---------------------------------------------------------------------------
__global__ __launch_bounds__(256, 4) void final_gemm(
    const unsigned short* __restrict__ aggU_, const unsigned short* __restrict__ featU_,
    const int* __restrict__ cntU_, const float* __restrict__ WU,
    const float* __restrict__ beU,
    const unsigned short* __restrict__ aggI_, const unsigned short* __restrict__ featI_,
    const int* __restrict__ cntI_, const float* __restrict__ WI,
    const float* __restrict__ beI,
    const float* __restrict__ loop_w, const float* __restrict__ h_bias,
    float* __restrict__ out)
{
    const int et = blockIdx.y;
    const unsigned short* __restrict__ agg  = et ? aggI_ : aggU_;
    const unsigned short* __restrict__ feat = et ? featI_ : featU_;
    const int* __restrict__ cntG            = et ? cntI_ : cntU_;
    const float* __restrict__ W             = et ? WI : WU;
    const float* __restrict__ b_et          = et ? beI : beU;
    float* __restrict__ outN = out + (et ? (size_t)N_USER * D : 0);

    __shared__ unsigned short sWt[64][72];   // W^T bf16:   sWt[n][k]
    __shared__ unsigned short sLt[64][72];   // loop^T bf16
    __shared__ float sbe[64], sbh[64];
    __shared__ int sCnt[64];

    const int tid = threadIdx.x;
    const int row0 = blockIdx.x * 64;

    for (int i = tid; i < 4096; i += 256) {
        int k = i >> 6, n = i & 63;
        sWt[n][k] = f32_to_bf16(W[i]);        // W[k][n]
        sLt[n][k] = f32_to_bf16(loop_w[i]);
    }
    if (tid < 64) {
        sbe[tid] = b_et[tid];
        sbh[tid] = h_bias[tid];
        int r = row0 + tid;
        sCnt[tid] = (r < N_NODE) ? cntG[r] : 0;
    }
    __syncthreads();

    const int wave = tid >> 6;
    const int lane = tid & 63;
    const int quad = lane >> 4;
    const int l16  = lane & 15;

    const int rowA = row0 + wave * 16 + l16;
    const int rA = (rowA < N_NODE) ? rowA : (N_NODE - 1);
    short8 aAgg0  = *(const short8*)(agg  + (size_t)rA * 64 +      quad * 8);
    short8 aAgg1  = *(const short8*)(agg  + (size_t)rA * 64 + 32 + quad * 8);
    short8 aFeat0 = *(const short8*)(feat + (size_t)rA * 64 +      quad * 8);
    short8 aFeat1 = *(const short8*)(feat + (size_t)rA * 64 + 32 + quad * 8);

    floatx4 acc[4];
    #pragma unroll
    for (int t = 0; t < 4; ++t) {
        const int n = t * 16 + l16;
        short8 bW0 = *(const short8*)&sWt[n][     quad * 8];
        short8 bW1 = *(const short8*)&sWt[n][32 + quad * 8];
        short8 bL0 = *(const short8*)&sLt[n][     quad * 8];
        short8 bL1 = *(const short8*)&sLt[n][32 + quad * 8];
        floatx4 a = {0.f, 0.f, 0.f, 0.f};
        a = __builtin_amdgcn_mfma_f32_16x16x32_bf16(aAgg0,  bW0, a, 0, 0, 0);
        a = __builtin_amdgcn_mfma_f32_16x16x32_bf16(aAgg1,  bW1, a, 0, 0, 0);
        a = __builtin_amdgcn_mfma_f32_16x16x32_bf16(aFeat0, bL0, a, 0, 0, 0);
        a = __builtin_amdgcn_mfma_f32_16x16x32_bf16(aFeat1, bL1, a, 0, 0, 0);
        acc[t] = a;
    }

    #pragma unroll
    for (int t = 0; t < 4; ++t) {
        const int col = t * 16 + l16;
        const float bh = sbh[col], be = sbe[col];
        #pragma unroll
        for (int i = 0; i < 4; ++i) {
            int lrow = wave * 16 + quad * 4 + i;
            int r = row0 + lrow;
            if (r < N_NODE) {
                float v = acc[t][i] + bh + (sCnt[lrow] > 0 ? be : 0.f);
                outN[(size_t)r * D + col] = v;
            }
        }
    }
}

// ---------------------------------------------------------------------------
extern "C" void kernel_launch(void* const* d_in, const int* in_sizes, int n_in,
                              void* d_out, int out_size, void* d_ws, size_t ws_size,
                              hipStream_t stream)
{
    const float* user_feat = (const float*)d_in[0];
    const float* item_feat = (const float*)d_in[1];
    const int*   rate_src  = (const int*)d_in[2];
    const int*   rate_dst  = (const int*)d_in[3];
    const int*   rev_src   = (const int*)d_in[4];
    const int*   rev_dst   = (const int*)d_in[5];
    const float* W_rate    = (const float*)d_in[6];
    const float* b_rate    = (const float*)d_in[7];
    const float* W_rev     = (const float*)d_in[8];
    const float* b_rev     = (const float*)d_in[9];
    const float* loop_w    = (const float*)d_in[10];
    const float* h_bias    = (const float*)d_in[11];
    float* out = (float*)d_out;

    // workspace layout (~51 MB)
    char* p = (char*)d_ws;
    ushort4* userB = (ushort4*)p; p += (size_t)N_USER * D * 2;                 // 6.4 MB
    ushort4* itemB = (ushort4*)p; p += (size_t)N_ITEM * D * 2;                 // 6.4 MB
    unsigned* binI = (unsigned*)p; p += (size_t)N_FINE * CAP * 4;              // 8.2 MB
    unsigned* binU = (unsigned*)p; p += (size_t)N_FINE * CAP * 4;              // 8.2 MB
    unsigned short* srtI = (unsigned short*)p; p += (size_t)N_FINE * CAP * 2;  // 4.1 MB
    unsigned short* srtU = (unsigned short*)p; p += (size_t)N_FINE * CAP * 2;  // 4.1 MB
    ushort4* aggI  = (ushort4*)p; p += (size_t)N_NODE * D * 2;                 // 6.4 MB
    ushort4* aggU  = (ushort4*)p; p += (size_t)N_NODE * D * 2;                 // 6.4 MB
    int* offI = (int*)p; p += (size_t)N_NODE * 4;
    int* offU = (int*)p; p += (size_t)N_NODE * 4;
    int* cntI = (int*)p; p += (size_t)N_NODE * 4;
    int* cntU = (int*)p; p += (size_t)N_NODE * 4;
    int* fcur = (int*)p; p += (size_t)(2 * N_FINE) * 4;
    (void)ws_size;

    // fcur = per-bucket counts, zero-init (3.2 KB)
    hipMemsetAsync(fcur, 0, (size_t)(2 * N_FINE) * sizeof(int), stream);

    // 1) merged binning (blocks [0, 2*NBIN) — dispatched first, latency-bound)
    //    + cast (blocks [2*NBIN, 2*NBIN + 2*NCAST) — BW-bound, overlaps)
    cast_bin<<<dim3(2 * NBIN + 2 * NCAST), 256, 0, stream>>>(
        (const float4*)user_feat, userB, (const float4*)item_feat, itemB,
        rate_src, rate_dst, binI,
        rev_src,  rev_dst,  binU, fcur);

    // 2) per-bucket counting sort -> u16 srt + off/cnt
    bucket_sort<<<dim3(N_FINE, 2), 256, 0, stream>>>(
        binI, srtI, offI, cntI,
        binU, srtU, offU, cntU, fcur);

    // 3) raw-feature segment mean (bf16, unroll-4)
    aggregate_kernel<<<(N_USER + N_ITEM + 15) / 16, 256, 0, stream>>>(
        itemB, userB,
        offU, cntU, srtU,
        offI, cntI, srtI,
        aggU, aggI);

    // 4) final dual GEMM via MFMA (merged, fully writes d_out)
    final_gemm<<<dim3((N_NODE + 63) / 64, 2), 256, 0, stream>>>(
        (const unsigned short*)aggU, (const unsigned short*)userB, cntU, W_rev, b_rev,
        (const unsigned short*)aggI, (const unsigned short*)itemB, cntI, W_rate, b_rate,
        loop_w, h_bias, out);

    (void)in_sizes; (void)n_in; (void)out_size;
}